// Round 7
// baseline (260.036 us; speedup 1.0000x reference)
//
#include <hip/hip_runtime.h>
#include <math.h>

#define S_LEN 256
#define BATCH 512
#define ROWS (S_LEN * BATCH)
#define VOCAB 128000

// ---------------------------------------------------------------------------
// Compile-time reproduction of np.random.RandomState(seed) op streams.
// ---------------------------------------------------------------------------
struct MTState {
    unsigned mt[624];
    int idx;
    constexpr MTState(unsigned seed) : mt{}, idx(624) {
        mt[0] = seed;
        for (int i = 1; i < 624; ++i)
            mt[i] = 1812433253u * (mt[i - 1] ^ (mt[i - 1] >> 30)) + (unsigned)i;
    }
    constexpr unsigned next() {
        if (idx >= 624) {
            for (int i = 0; i < 624; ++i) {
                unsigned y = (mt[i] & 0x80000000u) | (mt[(i + 1) % 624] & 0x7fffffffu);
                mt[i] = mt[(i + 397) % 624] ^ (y >> 1) ^ ((y & 1u) ? 2567483615u : 0u);
            }
            idx = 0;
        }
        unsigned y = mt[idx++];
        y ^= y >> 11;
        y ^= (y << 7)  & 2636928640u;
        y ^= (y << 15) & 4022730752u;
        y ^= y >> 18;
        return y;
    }
};

struct OpsTab {
    int   k [4][20];
    int   w0[4][20];
    int   w1[4][20];
    float t [4][20];
};

constexpr OpsTab make_ops() {
    OpsTab o{};
    for (int seed = 0; seed < 4; ++seed) {
        MTState rng((unsigned)seed);
        for (int i = 0; i < 20; ++i) {
            unsigned k = rng.next() & 3u;            // randint(4)
            if (k < 3u) {
                int w = (int)(rng.next() & 3u);      // randint(4)
                unsigned A = rng.next(), B = rng.next();  // rk_double
                double d = ((double)(A >> 5) * 67108864.0 + (double)(B >> 6))
                           / 9007199254740992.0;
                o.k[seed][i]  = (int)k;
                o.w0[seed][i] = w;
                o.w1[seed][i] = 0;
                o.t[seed][i]  = (float)(6.283185307179586 * d);
            } else {
                int w0 = (int)(rng.next() & 3u);     // randint(4)
                unsigned v = rng.next() & 3u;        // randint(3): reject >2
                while (v > 2u) v = rng.next() & 3u;
                o.k[seed][i]  = 3;
                o.w0[seed][i] = w0;
                o.w1[seed][i] = (int)((w0 + 1 + (int)v) & 3);
                o.t[seed][i]  = 0.f;
            }
        }
    }
    return o;
}

__constant__ OpsTab OPS = make_ops();

// factor for product-to-sum expansion: enc_j*enc_k per wire.
// t: 0->const, 1->cos, 2->sin basis.  bj,bk: wire bits of j,k.
__device__ inline float pfac(int t, int bj, int bk) {
    if (bj == bk)
        return (t == 0) ? 0.5f : (t == 1) ? (bj ? -0.5f : 0.5f) : 0.f;
    return (t == 2) ? 0.5f : 0.f;
}

// ---------------------------------------------------------------------------
// Setup: lane-parallel circuit fold -> M (LDS) -> Q = Re(M^T D_w M) -> T
// tensor (16 (g,w) pairs x 81 coeffs over {1,cos,sin}^4) -> global.
// Wire w <-> bit (3-w) of the state index.
// ---------------------------------------------------------------------------
__global__ __launch_bounds__(1024) void setup_kernel(const float* __restrict__ qrx,
                                                     const float* __restrict__ qry,
                                                     const float* __restrict__ qrz,
                                                     const float* __restrict__ qcrx,
                                                     float* __restrict__ Tg) {
    __shared__ float Mr[4 * 256];
    __shared__ float Mi[4 * 256];
    __shared__ float Q[16 * 256];

    int tid = threadIdx.x;
    int wv  = tid >> 6;
    int l   = tid & 63;
    int g   = wv >> 2;
    int r   = l & 15;
    int col = (wv & 3) * 4 + (l >> 4);

    float ar = (r == col) ? 1.f : 0.f;
    float ai = 0.f;
    int lbase = l & 48;

    // --- random layer (runtime loop, wave-uniform branches on k) ---
    for (int o = 0; o < 20; ++o) {
        int   k  = OPS.k[g][o];
        int   w  = OPS.w0[g][o];
        float th = OPS.t[g][o];
        if (k == 3) {
            int M1  = 8 >> OPS.w1[g][o];
            int M0  = 8 >> w;
            int src = lbase | (r ^ M1);
            float br = __shfl(ar, src, 64);
            float bi = __shfl(ai, src, 64);
            bool ctrl = (r & M0) != 0;
            ar = ctrl ? br : ar;
            ai = ctrl ? bi : ai;
        } else {
            int M = 8 >> w;
            float c = cosf(0.5f * th), s = sinf(0.5f * th);
            bool hi = (r & M) != 0;
            float Ar = c, Ai = 0.f, Br = 0.f, Bi = 0.f;
            if (k == 0) { Bi = -s; }                       // RX
            else if (k == 1) { Br = hi ? s : -s; }         // RY
            else { Ai = hi ? s : -s; }                     // RZ
            int src = lbase | (r ^ M);
            float br = __shfl(ar, src, 64);
            float bi = __shfl(ai, src, 64);
            float nr = Ar * ar - Ai * ai + Br * br - Bi * bi;
            float ni = Ar * ai + Ai * ar + Br * bi + Bi * br;
            ar = nr; ai = ni;
        }
    }

    // --- trainable ring (runtime loop over wires) ---
    for (int w = 0; w < 4; ++w) {
        int M  = 8 >> w;
        int M1 = 8 >> ((w + 1) & 3);
        bool hi = (r & M) != 0;
        int src = lbase | (r ^ M);
        float th, c, s, br, bi, nr, ni;

        th = qrx[g * 4 + w]; c = cosf(0.5f * th); s = sinf(0.5f * th);
        br = __shfl(ar, src, 64); bi = __shfl(ai, src, 64);
        nr = c * ar + s * bi;  ni = c * ai - s * br;       // RX: B = -i s
        ar = nr; ai = ni;

        th = qry[g * 4 + w]; c = cosf(0.5f * th); s = sinf(0.5f * th);
        br = __shfl(ar, src, 64); bi = __shfl(ai, src, 64);
        { float B = hi ? s : -s;
          nr = c * ar + B * br;  ni = c * ai + B * bi; }   // RY
        ar = nr; ai = ni;

        th = qrz[g * 4 + w]; c = cosf(0.5f * th); s = sinf(0.5f * th);
        { float Ai2 = hi ? s : -s;
          nr = c * ar - Ai2 * ai;  ni = c * ai + Ai2 * ar; } // RZ
        ar = nr; ai = ni;

        th = qcrx[g * 4 + w]; c = cosf(0.5f * th); s = sinf(0.5f * th);
        int src1 = lbase | (r ^ M1);
        br = __shfl(ar, src1, 64); bi = __shfl(ai, src1, 64);
        bool ctrl = hi;
        nr = c * ar + s * bi;  ni = c * ai - s * br;       // CRX on target
        ar = ctrl ? nr : ar;
        ai = ctrl ? ni : ai;
    }

    Mr[g * 256 + r * 16 + col] = ar;
    Mi[g * 256 + r * 16 + col] = ai;
    __syncthreads();

    // Q[gw][j][k] = sum_r sigma_w(r) * (Mr[g][r][j]Mr[g][r][k] + Mi..Mi)
    for (int n = 0; n < 4; ++n) {
        int i  = tid * 4 + n;
        int gw = i >> 8, j = (i >> 4) & 15, kk = i & 15;
        int gg2 = gw >> 2, w = gw & 3;
        float acc = 0.f;
        for (int rr = 0; rr < 16; ++rr) {
            float sgn = ((rr >> (3 - w)) & 1) ? -1.f : 1.f;
            float mrj = Mr[gg2 * 256 + rr * 16 + j], mrk = Mr[gg2 * 256 + rr * 16 + kk];
            float mij = Mi[gg2 * 256 + rr * 16 + j], mik = Mi[gg2 * 256 + rr * 16 + kk];
            acc += sgn * (mrj * mrk + mij * mik);
        }
        Q[gw * 256 + j * 16 + kk] = acc;
    }
    __syncthreads();

    // T[gw][t0][t1][t2][t3] = sum_{j,k} Q[gw][j][k] * prod_w pfac(tw, bjw, bkw)
    if (tid < 144) {
        int gw = tid / 9, rem = tid % 9, t0 = rem / 3, t1 = rem % 3;
        float acc[3][3] = {};
        for (int jk = 0; jk < 256; ++jk) {
            int j = jk >> 4, kq = jk & 15;
            int bj0 = (j >> 3) & 1, bk0 = (kq >> 3) & 1;
            int bj1 = (j >> 2) & 1, bk1 = (kq >> 2) & 1;
            int bj2 = (j >> 1) & 1, bk2 = (kq >> 1) & 1;
            int bj3 = j & 1,        bk3 = kq & 1;
            float f01 = pfac(t0, bj0, bk0) * pfac(t1, bj1, bk1);
            float base = Q[gw * 256 + jk] * f01;
#pragma unroll
            for (int t2 = 0; t2 < 3; ++t2) {
                float f2 = pfac(t2, bj2, bk2);
#pragma unroll
                for (int t3 = 0; t3 < 3; ++t3) {
                    float f3 = pfac(t3, bj3, bk3);
                    acc[t2][t3] = fmaf(base, f2 * f3, acc[t2][t3]);
                }
            }
        }
#pragma unroll
        for (int t2 = 0; t2 < 3; ++t2)
#pragma unroll
            for (int t3 = 0; t3 < 3; ++t3)
                Tg[gw * 81 + t0 * 27 + t1 * 9 + t2 * 3 + t3] = acc[t2][t3];
    }
}

// ---------------------------------------------------------------------------
// proj kernel: proj[v][q] = emb[v] . lin_w[q,:256] + lin_b[q] for ALL vocab.
// Streaming GEMM — perfectly coalesced sequential reads of emb (131 MB),
// no latency sensitivity (vs the old per-token random gather at 664 GB/s).
// Wave per vocab row; lane = (chunk = l>>4 of 64 d's, q = l&15); weights
// register-resident.
// ---------------------------------------------------------------------------
__global__ __launch_bounds__(256) void proj_kernel(const float* __restrict__ emb,
                                                   const float* __restrict__ lin_w,
                                                   const float* __restrict__ lin_b,
                                                   float* __restrict__ proj) {
    int l  = threadIdx.x & 63;
    int q  = l & 15;
    int ch = l >> 4;
    int wid = (blockIdx.x * blockDim.x + threadIdx.x) >> 6;
    int nw  = (gridDim.x * blockDim.x) >> 6;

    const float* wr = lin_w + q * 260 + ch * 64;
    float w0[16], w1[16], w2[16], w3[16];
#pragma unroll
    for (int j = 0; j < 16; ++j) {
        float4 t = *(const float4*)(wr + j * 4);
        w0[j] = t.x; w1[j] = t.y; w2[j] = t.z; w3[j] = t.w;
    }
    float bias = lin_b[q];

    for (int v = wid; v < VOCAB; v += nw) {
        const float* er = emb + (size_t)v * 256 + ch * 64;
        float acc = 0.f;
#pragma unroll
        for (int j = 0; j < 16; ++j) {
            float4 x = *(const float4*)(er + j * 4);
            acc = fmaf(x.x, w0[j], acc);
            acc = fmaf(x.y, w1[j], acc);
            acc = fmaf(x.z, w2[j], acc);
            acc = fmaf(x.w, w3[j], acc);
        }
        acc += __shfl_xor(acc, 16, 64);
        acc += __shfl_xor(acc, 32, 64);
        if (l < 16) proj[(size_t)v * 16 + q] = acc + bias;
    }
}

// ---------------------------------------------------------------------------
// Recurrence: lane l = (q<<4)|(w<<2)|g — 4 chains/wave, lane owns Z^{g,w}
// via the 81-term polynomial.  Cross-lane per step: 4 DPP quad broadcasts +
// 3 DPP row_ror (weights pre-permuted).  The angx gather is folded in: tok
// prefetched 8 steps ahead, proj row 4 steps ahead — both chained loads are
// fully hidden under ~4 steps of compute.
// ---------------------------------------------------------------------------
__global__ __launch_bounds__(64) void lstm_kernel(const float* __restrict__ lin_w,
                                                  const float* __restrict__ Tg,
                                                  const int* __restrict__ sent,
                                                  const float* __restrict__ proj,
                                                  float* __restrict__ outs) {
    int l = threadIdx.x;
    int g = l & 3;
    int w = (l >> 2) & 3;
    int q = l >> 4;
    int b = blockIdx.x * 4 + q;

    float T[81];
#pragma unroll
    for (int i = 0; i < 81; ++i) T[i] = Tg[(g * 4 + w) * 81 + i];

    // whp[q][k] = whh[q][(w-k)&3] so that a_q = ax.q + sum_k whp[q][k]*hr_k
    // with hr_k = h_{(w-k)&3} delivered by DPP row_ror:4k.
    float whp[4][4];
#pragma unroll
    for (int qq = 0; qq < 4; ++qq)
#pragma unroll
        for (int k = 0; k < 4; ++k)
            whp[qq][k] = lin_w[(g * 4 + qq) * 260 + 256 + ((w - k) & 3)];

    const float kk = (g == 2) ? 2.f : 1.f;
    const float sc = (g == 2) ? 2.f : 1.f;
    const float of = (g == 2) ? 1.f : 0.f;

    float hr0 = 0.f, hr1 = 0.f, hr2 = 0.f, hr3 = 0.f, cst = 0.f;

    const int* sp = sent + b;                          // token for step s: sp[s*512]
    float* op = outs + (size_t)b * 4 + w;              // step stride 2048 floats

    auto tokat = [&](int sidx) { return sp[(size_t)(sidx & 255) * BATCH]; };
    auto rowat = [&](int tok)  { return *(const float4*)(proj + (size_t)tok * 16 + g * 4); };

    int tk0 = tokat(4), tk1 = tokat(5), tk2 = tokat(6), tk3 = tokat(7);
    float4 A0 = rowat(tokat(0));
    float4 A1 = rowat(tokat(1));
    float4 A2 = rowat(tokat(2));
    float4 A3 = rowat(tokat(3));

    auto step = [&](float4 ax, int sidx) {
        float a0 = fmaf(whp[0][3], hr3, fmaf(whp[0][2], hr2, fmaf(whp[0][1], hr1, fmaf(whp[0][0], hr0, ax.x))));
        float a1 = fmaf(whp[1][3], hr3, fmaf(whp[1][2], hr2, fmaf(whp[1][1], hr1, fmaf(whp[1][0], hr0, ax.y))));
        float a2 = fmaf(whp[2][3], hr3, fmaf(whp[2][2], hr2, fmaf(whp[2][1], hr1, fmaf(whp[2][0], hr0, ax.z))));
        float a3 = fmaf(whp[3][3], hr3, fmaf(whp[3][2], hr2, fmaf(whp[3][1], hr1, fmaf(whp[3][0], hr0, ax.w))));

        float c0 = __cosf(a0), s0 = __sinf(a0);
        float c1 = __cosf(a1), s1 = __sinf(a1);
        float c2 = __cosf(a2), s2 = __sinf(a2);
        float c3 = __cosf(a3), s3 = __sinf(a3);

        float yA[27];
#pragma unroll
        for (int i = 0; i < 27; ++i)
            yA[i] = fmaf(s3, T[i * 3 + 2], fmaf(c3, T[i * 3 + 1], T[i * 3]));
        float yB[9];
#pragma unroll
        for (int i = 0; i < 9; ++i)
            yB[i] = fmaf(s2, yA[i * 3 + 2], fmaf(c2, yA[i * 3 + 1], yA[i * 3]));
        float yC[3];
#pragma unroll
        for (int i = 0; i < 3; ++i)
            yC[i] = fmaf(s1, yB[i * 3 + 2], fmaf(c1, yB[i * 3 + 1], yB[i * 3]));
        float Z = fmaf(s0, yC[2], fmaf(c0, yC[1], yC[0]));

        float sg  = 1.f / (1.f + __expf(-kk * Z));
        float act = sc * sg - of;

        int ai2 = __float_as_int(act);
        float f  = __int_as_float(__builtin_amdgcn_update_dpp(0, ai2, 0x00, 0xf, 0xf, true));
        float ii = __int_as_float(__builtin_amdgcn_update_dpp(0, ai2, 0x55, 0xf, 0xf, true));
        float gg = __int_as_float(__builtin_amdgcn_update_dpp(0, ai2, 0xAA, 0xf, 0xf, true));
        float oo = __int_as_float(__builtin_amdgcn_update_dpp(0, ai2, 0xFF, 0xf, 0xf, true));

        cst = fmaf(f, cst, ii * gg);
        float tn = 2.f / (1.f + __expf(-2.f * cst)) - 1.f;
        float hme = oo * tn;

        if (g == 0) op[(size_t)sidx * 2048] = hme;

        int hi = __float_as_int(hme);
        hr0 = hme;
        hr1 = __int_as_float(__builtin_amdgcn_update_dpp(hi, hi, 0x124, 0xf, 0xf, false));
        hr2 = __int_as_float(__builtin_amdgcn_update_dpp(hi, hi, 0x128, 0xf, 0xf, false));
        hr3 = __int_as_float(__builtin_amdgcn_update_dpp(hi, hi, 0x12C, 0xf, 0xf, false));
    };

    for (int s = 0; s < S_LEN; s += 4) {
        step(A0, s);     A0 = rowat(tk0); tk0 = tokat(s + 8);
        step(A1, s + 1); A1 = rowat(tk1); tk1 = tokat(s + 9);
        step(A2, s + 2); A2 = rowat(tk2); tk2 = tokat(s + 10);
        step(A3, s + 3); A3 = rowat(tk3); tk3 = tokat(s + 11);
    }
}

// ---------------------------------------------------------------------------
// logits + log_softmax: wave per (s,b) row, lane = tag.
// ---------------------------------------------------------------------------
__global__ __launch_bounds__(256) void logits_kernel(const float* __restrict__ outs,
                                                     const float* __restrict__ tag_w,
                                                     const float* __restrict__ tag_b,
                                                     float* __restrict__ out) {
    int l = threadIdx.x & 63;
    int wid = (blockIdx.x * blockDim.x + threadIdx.x) >> 6;
    int nw  = (gridDim.x * blockDim.x) >> 6;

    float4 w = *(const float4*)(tag_w + l * 4);
    float bb = tag_b[l];

    for (int row = wid; row < ROWS; row += nw) {
        float4 h = *(const float4*)(outs + (size_t)row * 4);
        float z = fmaf(h.x, w.x, fmaf(h.y, w.y, fmaf(h.z, w.z, fmaf(h.w, w.w, bb))));
        float m = z;
#pragma unroll
        for (int d = 1; d < 64; d <<= 1) m = fmaxf(m, __shfl_xor(m, d, 64));
        float e = __expf(z - m);
        float ssum = e;
#pragma unroll
        for (int d = 1; d < 64; d <<= 1) ssum += __shfl_xor(ssum, d, 64);
        out[(size_t)row * 64 + l] = (z - m) - __logf(ssum);
    }
}

// ---------------------------------------------------------------------------
extern "C" void kernel_launch(void* const* d_in, const int* in_sizes, int n_in,
                              void* d_out, int out_size, void* d_ws, size_t ws_size,
                              hipStream_t stream) {
    const int*   sent  = (const int*)d_in[0];
    const float* emb   = (const float*)d_in[1];
    const float* lin_w = (const float*)d_in[2];
    const float* lin_b = (const float*)d_in[3];
    const float* qrx   = (const float*)d_in[4];
    const float* qry   = (const float*)d_in[5];
    const float* qrz   = (const float*)d_in[6];
    const float* qcrx  = (const float*)d_in[7];
    const float* tag_w = (const float*)d_in[8];
    const float* tag_b = (const float*)d_in[9];
    float* out = (float*)d_out;

    char* ws = (char*)d_ws;
    float*  Tg   = (float*)ws;                                     // 16*81*4 = 5184 B
    float*  proj = (float*)(ws + 8192);                            // VOCAB*16*4 = 8.192 MB
    float*  outs = (float*)(ws + 8192 + (size_t)VOCAB * 16 * 4);   // ROWS*4*4 = 2 MB

    setup_kernel<<<dim3(1), dim3(1024), 0, stream>>>(qrx, qry, qrz, qcrx, Tg);
    proj_kernel<<<dim3(1024), dim3(256), 0, stream>>>(emb, lin_w, lin_b, proj);
    lstm_kernel<<<dim3(128), dim3(64), 0, stream>>>(lin_w, Tg, sent, proj, outs);
    logits_kernel<<<dim3(1024), dim3(256), 0, stream>>>(outs, tag_w, tag_b, out);
}

// Round 8
// 214.108 us; speedup vs baseline: 1.2145x; 1.2145x over previous
//
#include <hip/hip_runtime.h>
#include <math.h>

#define S_LEN 256
#define BATCH 512
#define ROWS (S_LEN * BATCH)
#define VOCAB 128000

// ---------------------------------------------------------------------------
// Compile-time reproduction of np.random.RandomState(seed) op streams.
// ---------------------------------------------------------------------------
struct MTState {
    unsigned mt[624];
    int idx;
    constexpr MTState(unsigned seed) : mt{}, idx(624) {
        mt[0] = seed;
        for (int i = 1; i < 624; ++i)
            mt[i] = 1812433253u * (mt[i - 1] ^ (mt[i - 1] >> 30)) + (unsigned)i;
    }
    constexpr unsigned next() {
        if (idx >= 624) {
            for (int i = 0; i < 624; ++i) {
                unsigned y = (mt[i] & 0x80000000u) | (mt[(i + 1) % 624] & 0x7fffffffu);
                mt[i] = mt[(i + 397) % 624] ^ (y >> 1) ^ ((y & 1u) ? 2567483615u : 0u);
            }
            idx = 0;
        }
        unsigned y = mt[idx++];
        y ^= y >> 11;
        y ^= (y << 7)  & 2636928640u;
        y ^= (y << 15) & 4022730752u;
        y ^= y >> 18;
        return y;
    }
};

struct OpsTab {
    int   k [4][20];
    int   w0[4][20];
    int   w1[4][20];
    float t [4][20];
};

constexpr OpsTab make_ops() {
    OpsTab o{};
    for (int seed = 0; seed < 4; ++seed) {
        MTState rng((unsigned)seed);
        for (int i = 0; i < 20; ++i) {
            unsigned k = rng.next() & 3u;            // randint(4)
            if (k < 3u) {
                int w = (int)(rng.next() & 3u);      // randint(4)
                unsigned A = rng.next(), B = rng.next();  // rk_double
                double d = ((double)(A >> 5) * 67108864.0 + (double)(B >> 6))
                           / 9007199254740992.0;
                o.k[seed][i]  = (int)k;
                o.w0[seed][i] = w;
                o.w1[seed][i] = 0;
                o.t[seed][i]  = (float)(6.283185307179586 * d);
            } else {
                int w0 = (int)(rng.next() & 3u);     // randint(4)
                unsigned v = rng.next() & 3u;        // randint(3): reject >2
                while (v > 2u) v = rng.next() & 3u;
                o.k[seed][i]  = 3;
                o.w0[seed][i] = w0;
                o.w1[seed][i] = (int)((w0 + 1 + (int)v) & 3);
                o.t[seed][i]  = 0.f;
            }
        }
    }
    return o;
}

__constant__ OpsTab OPS = make_ops();

// factor for product-to-sum expansion: enc_j*enc_k per wire.
// t: 0->const, 1->cos, 2->sin basis.  bj,bk: wire bits of j,k.
__device__ inline float pfac(int t, int bj, int bk) {
    if (bj == bk)
        return (t == 0) ? 0.5f : (t == 1) ? (bj ? -0.5f : 0.5f) : 0.f;
    return (t == 2) ? 0.5f : 0.f;
}

// ---------------------------------------------------------------------------
// Setup: lane-parallel circuit fold -> M (LDS) -> Q = Re(M^T D_w M) -> T
// tensor (16 (g,w) pairs x 81 coeffs over {1,cos,sin}^4) -> global.
// Wire w <-> bit (3-w) of the state index.
// ---------------------------------------------------------------------------
__global__ __launch_bounds__(1024) void setup_kernel(const float* __restrict__ qrx,
                                                     const float* __restrict__ qry,
                                                     const float* __restrict__ qrz,
                                                     const float* __restrict__ qcrx,
                                                     float* __restrict__ Tg) {
    __shared__ float Mr[4 * 256];
    __shared__ float Mi[4 * 256];
    __shared__ float Q[16 * 256];

    int tid = threadIdx.x;
    int wv  = tid >> 6;
    int l   = tid & 63;
    int g   = wv >> 2;
    int r   = l & 15;
    int col = (wv & 3) * 4 + (l >> 4);

    float ar = (r == col) ? 1.f : 0.f;
    float ai = 0.f;
    int lbase = l & 48;

    // --- random layer (runtime loop, wave-uniform branches on k) ---
    for (int o = 0; o < 20; ++o) {
        int   k  = OPS.k[g][o];
        int   w  = OPS.w0[g][o];
        float th = OPS.t[g][o];
        if (k == 3) {
            int M1  = 8 >> OPS.w1[g][o];
            int M0  = 8 >> w;
            int src = lbase | (r ^ M1);
            float br = __shfl(ar, src, 64);
            float bi = __shfl(ai, src, 64);
            bool ctrl = (r & M0) != 0;
            ar = ctrl ? br : ar;
            ai = ctrl ? bi : ai;
        } else {
            int M = 8 >> w;
            float c = cosf(0.5f * th), s = sinf(0.5f * th);
            bool hi = (r & M) != 0;
            float Ar = c, Ai = 0.f, Br = 0.f, Bi = 0.f;
            if (k == 0) { Bi = -s; }                       // RX
            else if (k == 1) { Br = hi ? s : -s; }         // RY
            else { Ai = hi ? s : -s; }                     // RZ
            int src = lbase | (r ^ M);
            float br = __shfl(ar, src, 64);
            float bi = __shfl(ai, src, 64);
            float nr = Ar * ar - Ai * ai + Br * br - Bi * bi;
            float ni = Ar * ai + Ai * ar + Br * bi + Bi * br;
            ar = nr; ai = ni;
        }
    }

    // --- trainable ring (runtime loop over wires) ---
    for (int w = 0; w < 4; ++w) {
        int M  = 8 >> w;
        int M1 = 8 >> ((w + 1) & 3);
        bool hi = (r & M) != 0;
        int src = lbase | (r ^ M);
        float th, c, s, br, bi, nr, ni;

        th = qrx[g * 4 + w]; c = cosf(0.5f * th); s = sinf(0.5f * th);
        br = __shfl(ar, src, 64); bi = __shfl(ai, src, 64);
        nr = c * ar + s * bi;  ni = c * ai - s * br;       // RX: B = -i s
        ar = nr; ai = ni;

        th = qry[g * 4 + w]; c = cosf(0.5f * th); s = sinf(0.5f * th);
        br = __shfl(ar, src, 64); bi = __shfl(ai, src, 64);
        { float B = hi ? s : -s;
          nr = c * ar + B * br;  ni = c * ai + B * bi; }   // RY
        ar = nr; ai = ni;

        th = qrz[g * 4 + w]; c = cosf(0.5f * th); s = sinf(0.5f * th);
        { float Ai2 = hi ? s : -s;
          nr = c * ar - Ai2 * ai;  ni = c * ai + Ai2 * ar; } // RZ
        ar = nr; ai = ni;

        th = qcrx[g * 4 + w]; c = cosf(0.5f * th); s = sinf(0.5f * th);
        int src1 = lbase | (r ^ M1);
        br = __shfl(ar, src1, 64); bi = __shfl(ai, src1, 64);
        bool ctrl = hi;
        nr = c * ar + s * bi;  ni = c * ai - s * br;       // CRX on target
        ar = ctrl ? nr : ar;
        ai = ctrl ? ni : ai;
    }

    Mr[g * 256 + r * 16 + col] = ar;
    Mi[g * 256 + r * 16 + col] = ai;
    __syncthreads();

    // Q[gw][j][k] = sum_r sigma_w(r) * (Mr[g][r][j]Mr[g][r][k] + Mi..Mi)
    for (int n = 0; n < 4; ++n) {
        int i  = tid * 4 + n;
        int gw = i >> 8, j = (i >> 4) & 15, kk = i & 15;
        int gg2 = gw >> 2, w = gw & 3;
        float acc = 0.f;
        for (int rr = 0; rr < 16; ++rr) {
            float sgn = ((rr >> (3 - w)) & 1) ? -1.f : 1.f;
            float mrj = Mr[gg2 * 256 + rr * 16 + j], mrk = Mr[gg2 * 256 + rr * 16 + kk];
            float mij = Mi[gg2 * 256 + rr * 16 + j], mik = Mi[gg2 * 256 + rr * 16 + kk];
            acc += sgn * (mrj * mrk + mij * mik);
        }
        Q[gw * 256 + j * 16 + kk] = acc;
    }
    __syncthreads();

    // T[gw][t0][t1][t2][t3] = sum_{j,k} Q[gw][j][k] * prod_w pfac(tw, bjw, bkw)
    if (tid < 144) {
        int gw = tid / 9, rem = tid % 9, t0 = rem / 3, t1 = rem % 3;
        float acc[3][3] = {};
        for (int jk = 0; jk < 256; ++jk) {
            int j = jk >> 4, kq = jk & 15;
            int bj0 = (j >> 3) & 1, bk0 = (kq >> 3) & 1;
            int bj1 = (j >> 2) & 1, bk1 = (kq >> 2) & 1;
            int bj2 = (j >> 1) & 1, bk2 = (kq >> 1) & 1;
            int bj3 = j & 1,        bk3 = kq & 1;
            float f01 = pfac(t0, bj0, bk0) * pfac(t1, bj1, bk1);
            float base = Q[gw * 256 + jk] * f01;
#pragma unroll
            for (int t2 = 0; t2 < 3; ++t2) {
                float f2 = pfac(t2, bj2, bk2);
#pragma unroll
                for (int t3 = 0; t3 < 3; ++t3) {
                    float f3 = pfac(t3, bj3, bk3);
                    acc[t2][t3] = fmaf(base, f2 * f3, acc[t2][t3]);
                }
            }
        }
#pragma unroll
        for (int t2 = 0; t2 < 3; ++t2)
#pragma unroll
            for (int t3 = 0; t3 < 3; ++t3)
                Tg[gw * 81 + t0 * 27 + t1 * 9 + t2 * 3 + t3] = acc[t2][t3];
    }
}

// ---------------------------------------------------------------------------
// proj kernel: proj[v][q] = emb[v] . lin_w[q,:256] + lin_b[q] for ALL vocab.
// LDS-staged tile GEMM: block stages 16 emb rows (16KB) with perfectly
// coalesced distinct float4 loads (256 thr x 16B = 4KB/instr), then the
// (ch,q) compute mapping reads LDS where 16-lane same-address reads are free
// broadcasts.  Chunk stride 68 floats (+16B pad) -> the 4 distinct
// ds_read_b128 addresses hit disjoint banks.  Grid 2048 -> 100% occupancy.
// ---------------------------------------------------------------------------
#define TROWS 16
#define CH_STR 68                 // floats per chunk slot (64 + 4 pad)
#define ROW_STR (4 * CH_STR)      // 272 floats per row slot

__global__ __launch_bounds__(256) void proj_kernel(const float* __restrict__ emb,
                                                   const float* __restrict__ lin_w,
                                                   const float* __restrict__ lin_b,
                                                   float* __restrict__ proj) {
    __shared__ float lds[TROWS * ROW_STR];   // 17408 B

    int tid = threadIdx.x;
    int l   = tid & 63;
    int q   = l & 15;
    int ch  = l >> 4;
    int wv  = tid >> 6;

    const float* wr = lin_w + q * 260 + ch * 64;
    float w0[16], w1[16], w2[16], w3[16];
#pragma unroll
    for (int j = 0; j < 16; ++j) {
        float4 t = *(const float4*)(wr + j * 4);
        w0[j] = t.x; w1[j] = t.y; w2[j] = t.z; w3[j] = t.w;
    }
    float bias = lin_b[q];

    const int ntiles = VOCAB / TROWS;   // 8000
    for (int tile = blockIdx.x; tile < ntiles; tile += gridDim.x) {
        // stage 16 rows: thread handles float4 indices tid, tid+256, ... (4)
        const float4* src = (const float4*)(emb + (size_t)tile * TROWS * 256);
#pragma unroll
        for (int i = 0; i < 4; ++i) {
            int f4  = tid + i * 256;            // 0..1023
            int row = f4 >> 6;
            int c   = f4 & 63;
            float4 v = src[f4];
            *(float4*)(lds + row * ROW_STR + (c >> 4) * CH_STR + (c & 15) * 4) = v;
        }
        __syncthreads();

        // wave wv computes rows wv*4 .. wv*4+3
#pragma unroll
        for (int j = 0; j < 4; ++j) {
            int row = wv * 4 + j;
            const float* rp = lds + row * ROW_STR + ch * CH_STR;
            float acc = 0.f;
#pragma unroll
            for (int jj = 0; jj < 16; ++jj) {
                float4 x = *(const float4*)(rp + jj * 4);
                acc = fmaf(x.x, w0[jj], acc);
                acc = fmaf(x.y, w1[jj], acc);
                acc = fmaf(x.z, w2[jj], acc);
                acc = fmaf(x.w, w3[jj], acc);
            }
            acc += __shfl_xor(acc, 16, 64);
            acc += __shfl_xor(acc, 32, 64);
            if (l < 16) proj[(size_t)(tile * TROWS + row) * 16 + q] = acc + bias;
        }
        __syncthreads();
    }
}

// ---------------------------------------------------------------------------
// Recurrence: lane l = (q<<4)|(w<<2)|g — 4 chains/wave, lane owns Z^{g,w}
// via the 81-term polynomial.  Cross-lane per step: 4 DPP quad broadcasts +
// 3 DPP row_ror (weights pre-permuted).  The angx gather is folded in: tok
// prefetched 8 steps ahead, proj row 4 steps ahead — both chained loads are
// fully hidden under ~4 steps of compute.
// ---------------------------------------------------------------------------
__global__ __launch_bounds__(64) void lstm_kernel(const float* __restrict__ lin_w,
                                                  const float* __restrict__ Tg,
                                                  const int* __restrict__ sent,
                                                  const float* __restrict__ proj,
                                                  float* __restrict__ outs) {
    int l = threadIdx.x;
    int g = l & 3;
    int w = (l >> 2) & 3;
    int q = l >> 4;
    int b = blockIdx.x * 4 + q;

    float T[81];
#pragma unroll
    for (int i = 0; i < 81; ++i) T[i] = Tg[(g * 4 + w) * 81 + i];

    // whp[q][k] = whh[q][(w-k)&3] so that a_q = ax.q + sum_k whp[q][k]*hr_k
    // with hr_k = h_{(w-k)&3} delivered by DPP row_ror:4k.
    float whp[4][4];
#pragma unroll
    for (int qq = 0; qq < 4; ++qq)
#pragma unroll
        for (int k = 0; k < 4; ++k)
            whp[qq][k] = lin_w[(g * 4 + qq) * 260 + 256 + ((w - k) & 3)];

    const float kk = (g == 2) ? 2.f : 1.f;
    const float sc = (g == 2) ? 2.f : 1.f;
    const float of = (g == 2) ? 1.f : 0.f;

    float hr0 = 0.f, hr1 = 0.f, hr2 = 0.f, hr3 = 0.f, cst = 0.f;

    const int* sp = sent + b;                          // token for step s: sp[s*512]
    float* op = outs + (size_t)b * 4 + w;              // step stride 2048 floats

    auto tokat = [&](int sidx) { return sp[(size_t)(sidx & 255) * BATCH]; };
    auto rowat = [&](int tok)  { return *(const float4*)(proj + (size_t)tok * 16 + g * 4); };

    int tk0 = tokat(4), tk1 = tokat(5), tk2 = tokat(6), tk3 = tokat(7);
    float4 A0 = rowat(tokat(0));
    float4 A1 = rowat(tokat(1));
    float4 A2 = rowat(tokat(2));
    float4 A3 = rowat(tokat(3));

    auto step = [&](float4 ax, int sidx) {
        float a0 = fmaf(whp[0][3], hr3, fmaf(whp[0][2], hr2, fmaf(whp[0][1], hr1, fmaf(whp[0][0], hr0, ax.x))));
        float a1 = fmaf(whp[1][3], hr3, fmaf(whp[1][2], hr2, fmaf(whp[1][1], hr1, fmaf(whp[1][0], hr0, ax.y))));
        float a2 = fmaf(whp[2][3], hr3, fmaf(whp[2][2], hr2, fmaf(whp[2][1], hr1, fmaf(whp[2][0], hr0, ax.z))));
        float a3 = fmaf(whp[3][3], hr3, fmaf(whp[3][2], hr2, fmaf(whp[3][1], hr1, fmaf(whp[3][0], hr0, ax.w))));

        float c0 = __cosf(a0), s0 = __sinf(a0);
        float c1 = __cosf(a1), s1 = __sinf(a1);
        float c2 = __cosf(a2), s2 = __sinf(a2);
        float c3 = __cosf(a3), s3 = __sinf(a3);

        float yA[27];
#pragma unroll
        for (int i = 0; i < 27; ++i)
            yA[i] = fmaf(s3, T[i * 3 + 2], fmaf(c3, T[i * 3 + 1], T[i * 3]));
        float yB[9];
#pragma unroll
        for (int i = 0; i < 9; ++i)
            yB[i] = fmaf(s2, yA[i * 3 + 2], fmaf(c2, yA[i * 3 + 1], yA[i * 3]));
        float yC[3];
#pragma unroll
        for (int i = 0; i < 3; ++i)
            yC[i] = fmaf(s1, yB[i * 3 + 2], fmaf(c1, yB[i * 3 + 1], yB[i * 3]));
        float Z = fmaf(s0, yC[2], fmaf(c0, yC[1], yC[0]));

        float sg  = 1.f / (1.f + __expf(-kk * Z));
        float act = sc * sg - of;

        int ai2 = __float_as_int(act);
        float f  = __int_as_float(__builtin_amdgcn_update_dpp(0, ai2, 0x00, 0xf, 0xf, true));
        float ii = __int_as_float(__builtin_amdgcn_update_dpp(0, ai2, 0x55, 0xf, 0xf, true));
        float gg = __int_as_float(__builtin_amdgcn_update_dpp(0, ai2, 0xAA, 0xf, 0xf, true));
        float oo = __int_as_float(__builtin_amdgcn_update_dpp(0, ai2, 0xFF, 0xf, 0xf, true));

        cst = fmaf(f, cst, ii * gg);
        float tn = 2.f / (1.f + __expf(-2.f * cst)) - 1.f;
        float hme = oo * tn;

        if (g == 0) op[(size_t)sidx * 2048] = hme;

        int hi = __float_as_int(hme);
        hr0 = hme;
        hr1 = __int_as_float(__builtin_amdgcn_update_dpp(hi, hi, 0x124, 0xf, 0xf, false));
        hr2 = __int_as_float(__builtin_amdgcn_update_dpp(hi, hi, 0x128, 0xf, 0xf, false));
        hr3 = __int_as_float(__builtin_amdgcn_update_dpp(hi, hi, 0x12C, 0xf, 0xf, false));
    };

    for (int s = 0; s < S_LEN; s += 4) {
        step(A0, s);     A0 = rowat(tk0); tk0 = tokat(s + 8);
        step(A1, s + 1); A1 = rowat(tk1); tk1 = tokat(s + 9);
        step(A2, s + 2); A2 = rowat(tk2); tk2 = tokat(s + 10);
        step(A3, s + 3); A3 = rowat(tk3); tk3 = tokat(s + 11);
    }
}

// ---------------------------------------------------------------------------
// logits + log_softmax: wave per (s,b) row, lane = tag.
// ---------------------------------------------------------------------------
__global__ __launch_bounds__(256) void logits_kernel(const float* __restrict__ outs,
                                                     const float* __restrict__ tag_w,
                                                     const float* __restrict__ tag_b,
                                                     float* __restrict__ out) {
    int l = threadIdx.x & 63;
    int wid = (blockIdx.x * blockDim.x + threadIdx.x) >> 6;
    int nw  = (gridDim.x * blockDim.x) >> 6;

    float4 w = *(const float4*)(tag_w + l * 4);
    float bb = tag_b[l];

    for (int row = wid; row < ROWS; row += nw) {
        float4 h = *(const float4*)(outs + (size_t)row * 4);
        float z = fmaf(h.x, w.x, fmaf(h.y, w.y, fmaf(h.z, w.z, fmaf(h.w, w.w, bb))));
        float m = z;
#pragma unroll
        for (int d = 1; d < 64; d <<= 1) m = fmaxf(m, __shfl_xor(m, d, 64));
        float e = __expf(z - m);
        float ssum = e;
#pragma unroll
        for (int d = 1; d < 64; d <<= 1) ssum += __shfl_xor(ssum, d, 64);
        out[(size_t)row * 64 + l] = (z - m) - __logf(ssum);
    }
}

// ---------------------------------------------------------------------------
extern "C" void kernel_launch(void* const* d_in, const int* in_sizes, int n_in,
                              void* d_out, int out_size, void* d_ws, size_t ws_size,
                              hipStream_t stream) {
    const int*   sent  = (const int*)d_in[0];
    const float* emb   = (const float*)d_in[1];
    const float* lin_w = (const float*)d_in[2];
    const float* lin_b = (const float*)d_in[3];
    const float* qrx   = (const float*)d_in[4];
    const float* qry   = (const float*)d_in[5];
    const float* qrz   = (const float*)d_in[6];
    const float* qcrx  = (const float*)d_in[7];
    const float* tag_w = (const float*)d_in[8];
    const float* tag_b = (const float*)d_in[9];
    float* out = (float*)d_out;

    char* ws = (char*)d_ws;
    float*  Tg   = (float*)ws;                                     // 16*81*4 = 5184 B
    float*  proj = (float*)(ws + 8192);                            // VOCAB*16*4 = 8.192 MB
    float*  outs = (float*)(ws + 8192 + (size_t)VOCAB * 16 * 4);   // ROWS*4*4 = 2 MB

    setup_kernel<<<dim3(1), dim3(1024), 0, stream>>>(qrx, qry, qrz, qcrx, Tg);
    proj_kernel<<<dim3(2048), dim3(256), 0, stream>>>(emb, lin_w, lin_b, proj);
    lstm_kernel<<<dim3(128), dim3(64), 0, stream>>>(lin_w, Tg, sent, proj, outs);
    logits_kernel<<<dim3(1024), dim3(256), 0, stream>>>(outs, tag_w, tag_b, out);
}

// Round 9
// 205.348 us; speedup vs baseline: 1.2663x; 1.0427x over previous
//
#include <hip/hip_runtime.h>
#include <math.h>

#define S_LEN 256
#define BATCH 512
#define ROWS (S_LEN * BATCH)
#define VOCAB 128000

// ---------------------------------------------------------------------------
// Compile-time reproduction of np.random.RandomState(seed) op streams.
// ---------------------------------------------------------------------------
struct MTState {
    unsigned mt[624];
    int idx;
    constexpr MTState(unsigned seed) : mt{}, idx(624) {
        mt[0] = seed;
        for (int i = 1; i < 624; ++i)
            mt[i] = 1812433253u * (mt[i - 1] ^ (mt[i - 1] >> 30)) + (unsigned)i;
    }
    constexpr unsigned next() {
        if (idx >= 624) {
            for (int i = 0; i < 624; ++i) {
                unsigned y = (mt[i] & 0x80000000u) | (mt[(i + 1) % 624] & 0x7fffffffu);
                mt[i] = mt[(i + 397) % 624] ^ (y >> 1) ^ ((y & 1u) ? 2567483615u : 0u);
            }
            idx = 0;
        }
        unsigned y = mt[idx++];
        y ^= y >> 11;
        y ^= (y << 7)  & 2636928640u;
        y ^= (y << 15) & 4022730752u;
        y ^= y >> 18;
        return y;
    }
};

struct OpsTab {
    int   k [4][20];
    int   w0[4][20];
    int   w1[4][20];
    float t [4][20];
};

constexpr OpsTab make_ops() {
    OpsTab o{};
    for (int seed = 0; seed < 4; ++seed) {
        MTState rng((unsigned)seed);
        for (int i = 0; i < 20; ++i) {
            unsigned k = rng.next() & 3u;            // randint(4)
            if (k < 3u) {
                int w = (int)(rng.next() & 3u);      // randint(4)
                unsigned A = rng.next(), B = rng.next();  // rk_double
                double d = ((double)(A >> 5) * 67108864.0 + (double)(B >> 6))
                           / 9007199254740992.0;
                o.k[seed][i]  = (int)k;
                o.w0[seed][i] = w;
                o.w1[seed][i] = 0;
                o.t[seed][i]  = (float)(6.283185307179586 * d);
            } else {
                int w0 = (int)(rng.next() & 3u);     // randint(4)
                unsigned v = rng.next() & 3u;        // randint(3): reject >2
                while (v > 2u) v = rng.next() & 3u;
                o.k[seed][i]  = 3;
                o.w0[seed][i] = w0;
                o.w1[seed][i] = (int)((w0 + 1 + (int)v) & 3);
                o.t[seed][i]  = 0.f;
            }
        }
    }
    return o;
}

__constant__ OpsTab OPS = make_ops();

// factor for product-to-sum expansion: enc_j*enc_k per wire.
// t: 0->const, 1->cos, 2->sin basis.  bj,bk: wire bits of j,k.
__device__ inline float pfac(int t, int bj, int bk) {
    if (bj == bk)
        return (t == 0) ? 0.5f : (t == 1) ? (bj ? -0.5f : 0.5f) : 0.f;
    return (t == 2) ? 0.5f : 0.f;
}

// ---------------------------------------------------------------------------
// Setup: lane-parallel circuit fold -> M (LDS) -> Q = Re(M^T D_w M) -> T
// tensor (16 (g,w) pairs x 81 coeffs over {1,cos,sin}^4) -> global.
// Wire w <-> bit (3-w) of the state index.
// ---------------------------------------------------------------------------
__global__ __launch_bounds__(1024) void setup_kernel(const float* __restrict__ qrx,
                                                     const float* __restrict__ qry,
                                                     const float* __restrict__ qrz,
                                                     const float* __restrict__ qcrx,
                                                     float* __restrict__ Tg) {
    __shared__ float Mr[4 * 256];
    __shared__ float Mi[4 * 256];
    __shared__ float Q[16 * 256];

    int tid = threadIdx.x;
    int wv  = tid >> 6;
    int l   = tid & 63;
    int g   = wv >> 2;
    int r   = l & 15;
    int col = (wv & 3) * 4 + (l >> 4);

    float ar = (r == col) ? 1.f : 0.f;
    float ai = 0.f;
    int lbase = l & 48;

    // --- random layer (runtime loop, wave-uniform branches on k) ---
    for (int o = 0; o < 20; ++o) {
        int   k  = OPS.k[g][o];
        int   w  = OPS.w0[g][o];
        float th = OPS.t[g][o];
        if (k == 3) {
            int M1  = 8 >> OPS.w1[g][o];
            int M0  = 8 >> w;
            int src = lbase | (r ^ M1);
            float br = __shfl(ar, src, 64);
            float bi = __shfl(ai, src, 64);
            bool ctrl = (r & M0) != 0;
            ar = ctrl ? br : ar;
            ai = ctrl ? bi : ai;
        } else {
            int M = 8 >> w;
            float c = cosf(0.5f * th), s = sinf(0.5f * th);
            bool hi = (r & M) != 0;
            float Ar = c, Ai = 0.f, Br = 0.f, Bi = 0.f;
            if (k == 0) { Bi = -s; }                       // RX
            else if (k == 1) { Br = hi ? s : -s; }         // RY
            else { Ai = hi ? s : -s; }                     // RZ
            int src = lbase | (r ^ M);
            float br = __shfl(ar, src, 64);
            float bi = __shfl(ai, src, 64);
            float nr = Ar * ar - Ai * ai + Br * br - Bi * bi;
            float ni = Ar * ai + Ai * ar + Br * bi + Bi * br;
            ar = nr; ai = ni;
        }
    }

    // --- trainable ring (runtime loop over wires) ---
    for (int w = 0; w < 4; ++w) {
        int M  = 8 >> w;
        int M1 = 8 >> ((w + 1) & 3);
        bool hi = (r & M) != 0;
        int src = lbase | (r ^ M);
        float th, c, s, br, bi, nr, ni;

        th = qrx[g * 4 + w]; c = cosf(0.5f * th); s = sinf(0.5f * th);
        br = __shfl(ar, src, 64); bi = __shfl(ai, src, 64);
        nr = c * ar + s * bi;  ni = c * ai - s * br;       // RX: B = -i s
        ar = nr; ai = ni;

        th = qry[g * 4 + w]; c = cosf(0.5f * th); s = sinf(0.5f * th);
        br = __shfl(ar, src, 64); bi = __shfl(ai, src, 64);
        { float B = hi ? s : -s;
          nr = c * ar + B * br;  ni = c * ai + B * bi; }   // RY
        ar = nr; ai = ni;

        th = qrz[g * 4 + w]; c = cosf(0.5f * th); s = sinf(0.5f * th);
        { float Ai2 = hi ? s : -s;
          nr = c * ar - Ai2 * ai;  ni = c * ai + Ai2 * ar; } // RZ
        ar = nr; ai = ni;

        th = qcrx[g * 4 + w]; c = cosf(0.5f * th); s = sinf(0.5f * th);
        int src1 = lbase | (r ^ M1);
        br = __shfl(ar, src1, 64); bi = __shfl(ai, src1, 64);
        bool ctrl = hi;
        nr = c * ar + s * bi;  ni = c * ai - s * br;       // CRX on target
        ar = ctrl ? nr : ar;
        ai = ctrl ? ni : ai;
    }

    Mr[g * 256 + r * 16 + col] = ar;
    Mi[g * 256 + r * 16 + col] = ai;
    __syncthreads();

    // Q[gw][j][k] = sum_r sigma_w(r) * (Mr[g][r][j]Mr[g][r][k] + Mi..Mi)
    for (int n = 0; n < 4; ++n) {
        int i  = tid * 4 + n;
        int gw = i >> 8, j = (i >> 4) & 15, kk = i & 15;
        int gg2 = gw >> 2, w = gw & 3;
        float acc = 0.f;
        for (int rr = 0; rr < 16; ++rr) {
            float sgn = ((rr >> (3 - w)) & 1) ? -1.f : 1.f;
            float mrj = Mr[gg2 * 256 + rr * 16 + j], mrk = Mr[gg2 * 256 + rr * 16 + kk];
            float mij = Mi[gg2 * 256 + rr * 16 + j], mik = Mi[gg2 * 256 + rr * 16 + kk];
            acc += sgn * (mrj * mrk + mij * mik);
        }
        Q[gw * 256 + j * 16 + kk] = acc;
    }
    __syncthreads();

    // T[gw][t0][t1][t2][t3] = sum_{j,k} Q[gw][j][k] * prod_w pfac(tw, bjw, bkw)
    if (tid < 144) {
        int gw = tid / 9, rem = tid % 9, t0 = rem / 3, t1 = rem % 3;
        float acc[3][3] = {};
        for (int jk = 0; jk < 256; ++jk) {
            int j = jk >> 4, kq = jk & 15;
            int bj0 = (j >> 3) & 1, bk0 = (kq >> 3) & 1;
            int bj1 = (j >> 2) & 1, bk1 = (kq >> 2) & 1;
            int bj2 = (j >> 1) & 1, bk2 = (kq >> 1) & 1;
            int bj3 = j & 1,        bk3 = kq & 1;
            float f01 = pfac(t0, bj0, bk0) * pfac(t1, bj1, bk1);
            float base = Q[gw * 256 + jk] * f01;
#pragma unroll
            for (int t2 = 0; t2 < 3; ++t2) {
                float f2 = pfac(t2, bj2, bk2);
#pragma unroll
                for (int t3 = 0; t3 < 3; ++t3) {
                    float f3 = pfac(t3, bj3, bk3);
                    acc[t2][t3] = fmaf(base, f2 * f3, acc[t2][t3]);
                }
            }
        }
#pragma unroll
        for (int t2 = 0; t2 < 3; ++t2)
#pragma unroll
            for (int t3 = 0; t3 < 3; ++t3)
                Tg[gw * 81 + t0 * 27 + t1 * 9 + t2 * 3 + t3] = acc[t2][t3];
    }
}

// ---------------------------------------------------------------------------
// proj kernel: proj[v][q] = emb[v] . lin_w[q,:256] + lin_b[q] for ALL vocab.
// LDS-staged tile GEMM (see R7 notes): coalesced staging + LDS broadcast
// reads, chunk stride 68 floats to avoid bank conflicts.
// ---------------------------------------------------------------------------
#define TROWS 16
#define CH_STR 68                 // floats per chunk slot (64 + 4 pad)
#define ROW_STR (4 * CH_STR)      // 272 floats per row slot

__global__ __launch_bounds__(256) void proj_kernel(const float* __restrict__ emb,
                                                   const float* __restrict__ lin_w,
                                                   const float* __restrict__ lin_b,
                                                   float* __restrict__ proj) {
    __shared__ float lds[TROWS * ROW_STR];   // 17408 B

    int tid = threadIdx.x;
    int l   = tid & 63;
    int q   = l & 15;
    int ch  = l >> 4;
    int wv  = tid >> 6;

    const float* wr = lin_w + q * 260 + ch * 64;
    float w0[16], w1[16], w2[16], w3[16];
#pragma unroll
    for (int j = 0; j < 16; ++j) {
        float4 t = *(const float4*)(wr + j * 4);
        w0[j] = t.x; w1[j] = t.y; w2[j] = t.z; w3[j] = t.w;
    }
    float bias = lin_b[q];

    const int ntiles = VOCAB / TROWS;   // 8000
    for (int tile = blockIdx.x; tile < ntiles; tile += gridDim.x) {
        const float4* src = (const float4*)(emb + (size_t)tile * TROWS * 256);
#pragma unroll
        for (int i = 0; i < 4; ++i) {
            int f4  = tid + i * 256;            // 0..1023
            int row = f4 >> 6;
            int c   = f4 & 63;
            float4 v = src[f4];
            *(float4*)(lds + row * ROW_STR + (c >> 4) * CH_STR + (c & 15) * 4) = v;
        }
        __syncthreads();

#pragma unroll
        for (int j = 0; j < 4; ++j) {
            int row = wv * 4 + j;
            const float* rp = lds + row * ROW_STR + ch * CH_STR;
            float acc = 0.f;
#pragma unroll
            for (int jj = 0; jj < 16; ++jj) {
                float4 x = *(const float4*)(rp + jj * 4);
                acc = fmaf(x.x, w0[jj], acc);
                acc = fmaf(x.y, w1[jj], acc);
                acc = fmaf(x.z, w2[jj], acc);
                acc = fmaf(x.w, w3[jj], acc);
            }
            acc += __shfl_xor(acc, 16, 64);
            acc += __shfl_xor(acc, 32, 64);
            if (l < 16) proj[(size_t)(tile * TROWS + row) * 16 + q] = acc + bias;
        }
        __syncthreads();
    }
}

// ---------------------------------------------------------------------------
// Recurrence: lane l = (q<<4)|(w<<2)|g — 4 chains/wave, lane owns Z^{g,w}.
// __launch_bounds__(64,1): only 128 waves exist in the whole grid, so trade
// occupancy for max VGPRs -> T[81]/whp/prefetch regs stay register-resident
// (R8 post-mortem: VGPR_Count=80 meant T was re-loaded from L2 every step,
// ~80 loads on the 256-iteration serial chain = the 935cy/step mystery).
// ---------------------------------------------------------------------------
__device__ inline float fast_sig(float k, float x) {
    // 1/(1+exp(-k x)) with fast rcp (threshold 0.1 absmax; error ~1e-6)
    return __builtin_amdgcn_rcpf(1.f + __expf(-k * x));
}

__global__ __launch_bounds__(64, 1) void lstm_kernel(const float* __restrict__ lin_w,
                                                     const float* __restrict__ Tg,
                                                     const int* __restrict__ sent,
                                                     const float* __restrict__ proj,
                                                     float* __restrict__ outs) {
    int l = threadIdx.x;
    int g = l & 3;
    int w = (l >> 2) & 3;
    int q = l >> 4;
    int b = blockIdx.x * 4 + q;

    float T[81];
#pragma unroll
    for (int i = 0; i < 81; ++i) T[i] = Tg[(g * 4 + w) * 81 + i];

    // whp[q][k] = whh[q][(w-k)&3] so that a_q = ax.q + sum_k whp[q][k]*hr_k
    // with hr_k = h_{(w-k)&3} delivered by DPP row_ror:4k.
    float whp[4][4];
#pragma unroll
    for (int qq = 0; qq < 4; ++qq)
#pragma unroll
        for (int k = 0; k < 4; ++k)
            whp[qq][k] = lin_w[(g * 4 + qq) * 260 + 256 + ((w - k) & 3)];

    const float kk = (g == 2) ? 2.f : 1.f;
    const float sc = (g == 2) ? 2.f : 1.f;
    const float of = (g == 2) ? 1.f : 0.f;

    float hr0 = 0.f, hr1 = 0.f, hr2 = 0.f, hr3 = 0.f, cst = 0.f;

    const int* sp = sent + b;                          // token for step s: sp[s*512]
    float* op = outs + (size_t)b * 4 + w;              // step stride 2048 floats

    auto tokat = [&](int sidx) { return sp[(size_t)(sidx & 255) * BATCH]; };
    auto rowat = [&](int tok)  { return *(const float4*)(proj + (size_t)tok * 16 + g * 4); };

    int tk0 = tokat(4), tk1 = tokat(5), tk2 = tokat(6), tk3 = tokat(7);
    float4 A0 = rowat(tokat(0));
    float4 A1 = rowat(tokat(1));
    float4 A2 = rowat(tokat(2));
    float4 A3 = rowat(tokat(3));

    auto step = [&](float4 ax, int sidx) {
        float a0 = fmaf(whp[0][3], hr3, fmaf(whp[0][2], hr2, fmaf(whp[0][1], hr1, fmaf(whp[0][0], hr0, ax.x))));
        float a1 = fmaf(whp[1][3], hr3, fmaf(whp[1][2], hr2, fmaf(whp[1][1], hr1, fmaf(whp[1][0], hr0, ax.y))));
        float a2 = fmaf(whp[2][3], hr3, fmaf(whp[2][2], hr2, fmaf(whp[2][1], hr1, fmaf(whp[2][0], hr0, ax.z))));
        float a3 = fmaf(whp[3][3], hr3, fmaf(whp[3][2], hr2, fmaf(whp[3][1], hr1, fmaf(whp[3][0], hr0, ax.w))));

        float c0, s0, c1, s1, c2, s2, c3, s3;
        __sincosf(a0, &s0, &c0);
        __sincosf(a1, &s1, &c1);
        __sincosf(a2, &s2, &c2);
        __sincosf(a3, &s3, &c3);

        float yA[27];
#pragma unroll
        for (int i = 0; i < 27; ++i)
            yA[i] = fmaf(s3, T[i * 3 + 2], fmaf(c3, T[i * 3 + 1], T[i * 3]));
        float yB[9];
#pragma unroll
        for (int i = 0; i < 9; ++i)
            yB[i] = fmaf(s2, yA[i * 3 + 2], fmaf(c2, yA[i * 3 + 1], yA[i * 3]));
        float yC[3];
#pragma unroll
        for (int i = 0; i < 3; ++i)
            yC[i] = fmaf(s1, yB[i * 3 + 2], fmaf(c1, yB[i * 3 + 1], yB[i * 3]));
        float Z = fmaf(s0, yC[2], fmaf(c0, yC[1], yC[0]));

        float act = fmaf(sc, fast_sig(kk, Z), -of);

        int ai2 = __float_as_int(act);
        float f  = __int_as_float(__builtin_amdgcn_update_dpp(0, ai2, 0x00, 0xf, 0xf, true));
        float ii = __int_as_float(__builtin_amdgcn_update_dpp(0, ai2, 0x55, 0xf, 0xf, true));
        float gg = __int_as_float(__builtin_amdgcn_update_dpp(0, ai2, 0xAA, 0xf, 0xf, true));
        float oo = __int_as_float(__builtin_amdgcn_update_dpp(0, ai2, 0xFF, 0xf, 0xf, true));

        cst = fmaf(f, cst, ii * gg);
        float tn = fmaf(2.f, fast_sig(2.f, cst), -1.f);
        float hme = oo * tn;

        if (g == 0) op[(size_t)sidx * 2048] = hme;

        int hi = __float_as_int(hme);
        hr0 = hme;
        hr1 = __int_as_float(__builtin_amdgcn_update_dpp(hi, hi, 0x124, 0xf, 0xf, false));
        hr2 = __int_as_float(__builtin_amdgcn_update_dpp(hi, hi, 0x128, 0xf, 0xf, false));
        hr3 = __int_as_float(__builtin_amdgcn_update_dpp(hi, hi, 0x12C, 0xf, 0xf, false));
    };

    for (int s = 0; s < S_LEN; s += 4) {
        step(A0, s);     A0 = rowat(tk0); tk0 = tokat(s + 8);
        step(A1, s + 1); A1 = rowat(tk1); tk1 = tokat(s + 9);
        step(A2, s + 2); A2 = rowat(tk2); tk2 = tokat(s + 10);
        step(A3, s + 3); A3 = rowat(tk3); tk3 = tokat(s + 11);
    }
}

// ---------------------------------------------------------------------------
// logits + log_softmax: wave per (s,b) row, lane = tag.
// ---------------------------------------------------------------------------
__global__ __launch_bounds__(256) void logits_kernel(const float* __restrict__ outs,
                                                     const float* __restrict__ tag_w,
                                                     const float* __restrict__ tag_b,
                                                     float* __restrict__ out) {
    int l = threadIdx.x & 63;
    int wid = (blockIdx.x * blockDim.x + threadIdx.x) >> 6;
    int nw  = (gridDim.x * blockDim.x) >> 6;

    float4 w = *(const float4*)(tag_w + l * 4);
    float bb = tag_b[l];

    for (int row = wid; row < ROWS; row += nw) {
        float4 h = *(const float4*)(outs + (size_t)row * 4);
        float z = fmaf(h.x, w.x, fmaf(h.y, w.y, fmaf(h.z, w.z, fmaf(h.w, w.w, bb))));
        float m = z;
#pragma unroll
        for (int d = 1; d < 64; d <<= 1) m = fmaxf(m, __shfl_xor(m, d, 64));
        float e = __expf(z - m);
        float ssum = e;
#pragma unroll
        for (int d = 1; d < 64; d <<= 1) ssum += __shfl_xor(ssum, d, 64);
        out[(size_t)row * 64 + l] = (z - m) - __logf(ssum);
    }
}

// ---------------------------------------------------------------------------
extern "C" void kernel_launch(void* const* d_in, const int* in_sizes, int n_in,
                              void* d_out, int out_size, void* d_ws, size_t ws_size,
                              hipStream_t stream) {
    const int*   sent  = (const int*)d_in[0];
    const float* emb   = (const float*)d_in[1];
    const float* lin_w = (const float*)d_in[2];
    const float* lin_b = (const float*)d_in[3];
    const float* qrx   = (const float*)d_in[4];
    const float* qry   = (const float*)d_in[5];
    const float* qrz   = (const float*)d_in[6];
    const float* qcrx  = (const float*)d_in[7];
    const float* tag_w = (const float*)d_in[8];
    const float* tag_b = (const float*)d_in[9];
    float* out = (float*)d_out;

    char* ws = (char*)d_ws;
    float*  Tg   = (float*)ws;                                     // 16*81*4 = 5184 B
    float*  proj = (float*)(ws + 8192);                            // VOCAB*16*4 = 8.192 MB
    float*  outs = (float*)(ws + 8192 + (size_t)VOCAB * 16 * 4);   // ROWS*4*4 = 2 MB

    setup_kernel<<<dim3(1), dim3(1024), 0, stream>>>(qrx, qry, qrz, qcrx, Tg);
    proj_kernel<<<dim3(2048), dim3(256), 0, stream>>>(emb, lin_w, lin_b, proj);
    lstm_kernel<<<dim3(128), dim3(64), 0, stream>>>(lin_w, Tg, sent, proj, outs);
    logits_kernel<<<dim3(1024), dim3(256), 0, stream>>>(outs, tag_w, tag_b, out);
}

// Round 10
// 204.941 us; speedup vs baseline: 1.2688x; 1.0020x over previous
//
#include <hip/hip_runtime.h>
#include <math.h>

#define S_LEN 256
#define BATCH 512
#define ROWS (S_LEN * BATCH)
#define VOCAB 128000

// ---------------------------------------------------------------------------
// Compile-time reproduction of np.random.RandomState(seed) op streams.
// ---------------------------------------------------------------------------
struct MTState {
    unsigned mt[624];
    int idx;
    constexpr MTState(unsigned seed) : mt{}, idx(624) {
        mt[0] = seed;
        for (int i = 1; i < 624; ++i)
            mt[i] = 1812433253u * (mt[i - 1] ^ (mt[i - 1] >> 30)) + (unsigned)i;
    }
    constexpr unsigned next() {
        if (idx >= 624) {
            for (int i = 0; i < 624; ++i) {
                unsigned y = (mt[i] & 0x80000000u) | (mt[(i + 1) % 624] & 0x7fffffffu);
                mt[i] = mt[(i + 397) % 624] ^ (y >> 1) ^ ((y & 1u) ? 2567483615u : 0u);
            }
            idx = 0;
        }
        unsigned y = mt[idx++];
        y ^= y >> 11;
        y ^= (y << 7)  & 2636928640u;
        y ^= (y << 15) & 4022730752u;
        y ^= y >> 18;
        return y;
    }
};

struct OpsTab {
    int   k [4][20];
    int   w0[4][20];
    int   w1[4][20];
    float t [4][20];
};

constexpr OpsTab make_ops() {
    OpsTab o{};
    for (int seed = 0; seed < 4; ++seed) {
        MTState rng((unsigned)seed);
        for (int i = 0; i < 20; ++i) {
            unsigned k = rng.next() & 3u;            // randint(4)
            if (k < 3u) {
                int w = (int)(rng.next() & 3u);      // randint(4)
                unsigned A = rng.next(), B = rng.next();  // rk_double
                double d = ((double)(A >> 5) * 67108864.0 + (double)(B >> 6))
                           / 9007199254740992.0;
                o.k[seed][i]  = (int)k;
                o.w0[seed][i] = w;
                o.w1[seed][i] = 0;
                o.t[seed][i]  = (float)(6.283185307179586 * d);
            } else {
                int w0 = (int)(rng.next() & 3u);     // randint(4)
                unsigned v = rng.next() & 3u;        // randint(3): reject >2
                while (v > 2u) v = rng.next() & 3u;
                o.k[seed][i]  = 3;
                o.w0[seed][i] = w0;
                o.w1[seed][i] = (int)((w0 + 1 + (int)v) & 3);
                o.t[seed][i]  = 0.f;
            }
        }
    }
    return o;
}

__constant__ OpsTab OPS = make_ops();

// factor for product-to-sum expansion: enc_j*enc_k per wire.
// t: 0->const, 1->cos, 2->sin basis.  bj,bk: wire bits of j,k.
__device__ inline float pfac(int t, int bj, int bk) {
    if (bj == bk)
        return (t == 0) ? 0.5f : (t == 1) ? (bj ? -0.5f : 0.5f) : 0.f;
    return (t == 2) ? 0.5f : 0.f;
}

// ---------------------------------------------------------------------------
// Setup: lane-parallel circuit fold -> M (LDS) -> Q = Re(M^T D_w M) -> T
// tensor (16 (g,w) pairs x 81 coeffs over {1,cos,sin}^4) -> global.
// Wire w <-> bit (3-w) of the state index.
// ---------------------------------------------------------------------------
__global__ __launch_bounds__(1024) void setup_kernel(const float* __restrict__ qrx,
                                                     const float* __restrict__ qry,
                                                     const float* __restrict__ qrz,
                                                     const float* __restrict__ qcrx,
                                                     float* __restrict__ Tg) {
    __shared__ float Mr[4 * 256];
    __shared__ float Mi[4 * 256];
    __shared__ float Q[16 * 256];

    int tid = threadIdx.x;
    int wv  = tid >> 6;
    int l   = tid & 63;
    int g   = wv >> 2;
    int r   = l & 15;
    int col = (wv & 3) * 4 + (l >> 4);

    float ar = (r == col) ? 1.f : 0.f;
    float ai = 0.f;
    int lbase = l & 48;

    // --- random layer (runtime loop, wave-uniform branches on k) ---
    for (int o = 0; o < 20; ++o) {
        int   k  = OPS.k[g][o];
        int   w  = OPS.w0[g][o];
        float th = OPS.t[g][o];
        if (k == 3) {
            int M1  = 8 >> OPS.w1[g][o];
            int M0  = 8 >> w;
            int src = lbase | (r ^ M1);
            float br = __shfl(ar, src, 64);
            float bi = __shfl(ai, src, 64);
            bool ctrl = (r & M0) != 0;
            ar = ctrl ? br : ar;
            ai = ctrl ? bi : ai;
        } else {
            int M = 8 >> w;
            float c = cosf(0.5f * th), s = sinf(0.5f * th);
            bool hi = (r & M) != 0;
            float Ar = c, Ai = 0.f, Br = 0.f, Bi = 0.f;
            if (k == 0) { Bi = -s; }                       // RX
            else if (k == 1) { Br = hi ? s : -s; }         // RY
            else { Ai = hi ? s : -s; }                     // RZ
            int src = lbase | (r ^ M);
            float br = __shfl(ar, src, 64);
            float bi = __shfl(ai, src, 64);
            float nr = Ar * ar - Ai * ai + Br * br - Bi * bi;
            float ni = Ar * ai + Ai * ar + Br * bi + Bi * br;
            ar = nr; ai = ni;
        }
    }

    // --- trainable ring (runtime loop over wires) ---
    for (int w = 0; w < 4; ++w) {
        int M  = 8 >> w;
        int M1 = 8 >> ((w + 1) & 3);
        bool hi = (r & M) != 0;
        int src = lbase | (r ^ M);
        float th, c, s, br, bi, nr, ni;

        th = qrx[g * 4 + w]; c = cosf(0.5f * th); s = sinf(0.5f * th);
        br = __shfl(ar, src, 64); bi = __shfl(ai, src, 64);
        nr = c * ar + s * bi;  ni = c * ai - s * br;       // RX: B = -i s
        ar = nr; ai = ni;

        th = qry[g * 4 + w]; c = cosf(0.5f * th); s = sinf(0.5f * th);
        br = __shfl(ar, src, 64); bi = __shfl(ai, src, 64);
        { float B = hi ? s : -s;
          nr = c * ar + B * br;  ni = c * ai + B * bi; }   // RY
        ar = nr; ai = ni;

        th = qrz[g * 4 + w]; c = cosf(0.5f * th); s = sinf(0.5f * th);
        { float Ai2 = hi ? s : -s;
          nr = c * ar - Ai2 * ai;  ni = c * ai + Ai2 * ar; } // RZ
        ar = nr; ai = ni;

        th = qcrx[g * 4 + w]; c = cosf(0.5f * th); s = sinf(0.5f * th);
        int src1 = lbase | (r ^ M1);
        br = __shfl(ar, src1, 64); bi = __shfl(ai, src1, 64);
        bool ctrl = hi;
        nr = c * ar + s * bi;  ni = c * ai - s * br;       // CRX on target
        ar = ctrl ? nr : ar;
        ai = ctrl ? ni : ai;
    }

    Mr[g * 256 + r * 16 + col] = ar;
    Mi[g * 256 + r * 16 + col] = ai;
    __syncthreads();

    // Q[gw][j][k] = sum_r sigma_w(r) * (Mr[g][r][j]Mr[g][r][k] + Mi..Mi)
    for (int n = 0; n < 4; ++n) {
        int i  = tid * 4 + n;
        int gw = i >> 8, j = (i >> 4) & 15, kk = i & 15;
        int gg2 = gw >> 2, w = gw & 3;
        float acc = 0.f;
        for (int rr = 0; rr < 16; ++rr) {
            float sgn = ((rr >> (3 - w)) & 1) ? -1.f : 1.f;
            float mrj = Mr[gg2 * 256 + rr * 16 + j], mrk = Mr[gg2 * 256 + rr * 16 + kk];
            float mij = Mi[gg2 * 256 + rr * 16 + j], mik = Mi[gg2 * 256 + rr * 16 + kk];
            acc += sgn * (mrj * mrk + mij * mik);
        }
        Q[gw * 256 + j * 16 + kk] = acc;
    }
    __syncthreads();

    // T[gw][t0][t1][t2][t3] = sum_{j,k} Q[gw][j][k] * prod_w pfac(tw, bjw, bkw)
    if (tid < 144) {
        int gw = tid / 9, rem = tid % 9, t0 = rem / 3, t1 = rem % 3;
        float acc[3][3] = {};
        for (int jk = 0; jk < 256; ++jk) {
            int j = jk >> 4, kq = jk & 15;
            int bj0 = (j >> 3) & 1, bk0 = (kq >> 3) & 1;
            int bj1 = (j >> 2) & 1, bk1 = (kq >> 2) & 1;
            int bj2 = (j >> 1) & 1, bk2 = (kq >> 1) & 1;
            int bj3 = j & 1,        bk3 = kq & 1;
            float f01 = pfac(t0, bj0, bk0) * pfac(t1, bj1, bk1);
            float base = Q[gw * 256 + jk] * f01;
#pragma unroll
            for (int t2 = 0; t2 < 3; ++t2) {
                float f2 = pfac(t2, bj2, bk2);
#pragma unroll
                for (int t3 = 0; t3 < 3; ++t3) {
                    float f3 = pfac(t3, bj3, bk3);
                    acc[t2][t3] = fmaf(base, f2 * f3, acc[t2][t3]);
                }
            }
        }
#pragma unroll
        for (int t2 = 0; t2 < 3; ++t2)
#pragma unroll
            for (int t3 = 0; t3 < 3; ++t3)
                Tg[gw * 81 + t0 * 27 + t1 * 9 + t2 * 3 + t3] = acc[t2][t3];
    }
}

// ---------------------------------------------------------------------------
// proj kernel: proj[v][q] = emb[v] . lin_w[q,:256] + lin_b[q] for ALL vocab.
// LDS-staged tile GEMM (see R7 notes): coalesced staging + LDS broadcast
// reads, chunk stride 68 floats to avoid bank conflicts.
// ---------------------------------------------------------------------------
#define TROWS 16
#define CH_STR 68                 // floats per chunk slot (64 + 4 pad)
#define ROW_STR (4 * CH_STR)      // 272 floats per row slot

__global__ __launch_bounds__(256) void proj_kernel(const float* __restrict__ emb,
                                                   const float* __restrict__ lin_w,
                                                   const float* __restrict__ lin_b,
                                                   float* __restrict__ proj) {
    __shared__ float lds[TROWS * ROW_STR];   // 17408 B

    int tid = threadIdx.x;
    int l   = tid & 63;
    int q   = l & 15;
    int ch  = l >> 4;
    int wv  = tid >> 6;

    const float* wr = lin_w + q * 260 + ch * 64;
    float w0[16], w1[16], w2[16], w3[16];
#pragma unroll
    for (int j = 0; j < 16; ++j) {
        float4 t = *(const float4*)(wr + j * 4);
        w0[j] = t.x; w1[j] = t.y; w2[j] = t.z; w3[j] = t.w;
    }
    float bias = lin_b[q];

    const int ntiles = VOCAB / TROWS;   // 8000
    for (int tile = blockIdx.x; tile < ntiles; tile += gridDim.x) {
        const float4* src = (const float4*)(emb + (size_t)tile * TROWS * 256);
#pragma unroll
        for (int i = 0; i < 4; ++i) {
            int f4  = tid + i * 256;            // 0..1023
            int row = f4 >> 6;
            int c   = f4 & 63;
            float4 v = src[f4];
            *(float4*)(lds + row * ROW_STR + (c >> 4) * CH_STR + (c & 15) * 4) = v;
        }
        __syncthreads();

#pragma unroll
        for (int j = 0; j < 4; ++j) {
            int row = wv * 4 + j;
            const float* rp = lds + row * ROW_STR + ch * CH_STR;
            float acc = 0.f;
#pragma unroll
            for (int jj = 0; jj < 16; ++jj) {
                float4 x = *(const float4*)(rp + jj * 4);
                acc = fmaf(x.x, w0[jj], acc);
                acc = fmaf(x.y, w1[jj], acc);
                acc = fmaf(x.z, w2[jj], acc);
                acc = fmaf(x.w, w3[jj], acc);
            }
            acc += __shfl_xor(acc, 16, 64);
            acc += __shfl_xor(acc, 32, 64);
            if (l < 16) proj[(size_t)(tile * TROWS + row) * 16 + q] = acc + bias;
        }
        __syncthreads();
    }
}

// ---------------------------------------------------------------------------
// Recurrence: lane l = (q<<4)|(w<<2)|g — 4 chains/wave, lane owns Z^{g,w}.
// amdgpu_waves_per_eu(1,1): pins the scheduler's occupancy TARGET (not just
// the cap, which __launch_bounds__(64,1) alone sets and the heuristic
// ignores — R9 post-mortem: VGPR stayed 80 and T[81] spilled to scratch,
// ~550cy/step of reload stalls on the serial chain).  Only 128 waves exist
// in the grid, so 1 wave/EU costs nothing.
// ---------------------------------------------------------------------------
__device__ inline float fast_sig(float k, float x) {
    // 1/(1+exp(-k x)) with fast rcp (threshold 0.1 absmax; error ~1e-6)
    return __builtin_amdgcn_rcpf(1.f + __expf(-k * x));
}

__global__ __launch_bounds__(64)
__attribute__((amdgpu_waves_per_eu(1, 1)))
void lstm_kernel(const float* __restrict__ lin_w,
                 const float* __restrict__ Tg,
                 const int* __restrict__ sent,
                 const float* __restrict__ proj,
                 float* __restrict__ outs) {
    int l = threadIdx.x;
    int g = l & 3;
    int w = (l >> 2) & 3;
    int q = l >> 4;
    int b = blockIdx.x * 4 + q;

    float T[81];
#pragma unroll
    for (int i = 0; i < 81; ++i) T[i] = Tg[(g * 4 + w) * 81 + i];

    // whp[q][k] = whh[q][(w-k)&3] so that a_q = ax.q + sum_k whp[q][k]*hr_k
    // with hr_k = h_{(w-k)&3} delivered by DPP row_ror:4k.
    float whp[4][4];
#pragma unroll
    for (int qq = 0; qq < 4; ++qq)
#pragma unroll
        for (int k = 0; k < 4; ++k)
            whp[qq][k] = lin_w[(g * 4 + qq) * 260 + 256 + ((w - k) & 3)];

    const float kk = (g == 2) ? 2.f : 1.f;
    const float sc = (g == 2) ? 2.f : 1.f;
    const float of = (g == 2) ? 1.f : 0.f;

    float hr0 = 0.f, hr1 = 0.f, hr2 = 0.f, hr3 = 0.f, cst = 0.f;

    const int* sp = sent + b;                          // token for step s: sp[s*512]
    float* op = outs + (size_t)b * 4 + w;              // step stride 2048 floats

    auto tokat = [&](int sidx) { return sp[(size_t)(sidx & 255) * BATCH]; };
    auto rowat = [&](int tok)  { return *(const float4*)(proj + (size_t)tok * 16 + g * 4); };

    int tk0 = tokat(4), tk1 = tokat(5), tk2 = tokat(6), tk3 = tokat(7);
    float4 A0 = rowat(tokat(0));
    float4 A1 = rowat(tokat(1));
    float4 A2 = rowat(tokat(2));
    float4 A3 = rowat(tokat(3));

    auto step = [&](float4 ax, int sidx) {
        float a0 = fmaf(whp[0][3], hr3, fmaf(whp[0][2], hr2, fmaf(whp[0][1], hr1, fmaf(whp[0][0], hr0, ax.x))));
        float a1 = fmaf(whp[1][3], hr3, fmaf(whp[1][2], hr2, fmaf(whp[1][1], hr1, fmaf(whp[1][0], hr0, ax.y))));
        float a2 = fmaf(whp[2][3], hr3, fmaf(whp[2][2], hr2, fmaf(whp[2][1], hr1, fmaf(whp[2][0], hr0, ax.z))));
        float a3 = fmaf(whp[3][3], hr3, fmaf(whp[3][2], hr2, fmaf(whp[3][1], hr1, fmaf(whp[3][0], hr0, ax.w))));

        float c0, s0, c1, s1, c2, s2, c3, s3;
        __sincosf(a0, &s0, &c0);
        __sincosf(a1, &s1, &c1);
        __sincosf(a2, &s2, &c2);
        __sincosf(a3, &s3, &c3);

        float yA[27];
#pragma unroll
        for (int i = 0; i < 27; ++i)
            yA[i] = fmaf(s3, T[i * 3 + 2], fmaf(c3, T[i * 3 + 1], T[i * 3]));
        float yB[9];
#pragma unroll
        for (int i = 0; i < 9; ++i)
            yB[i] = fmaf(s2, yA[i * 3 + 2], fmaf(c2, yA[i * 3 + 1], yA[i * 3]));
        float yC[3];
#pragma unroll
        for (int i = 0; i < 3; ++i)
            yC[i] = fmaf(s1, yB[i * 3 + 2], fmaf(c1, yB[i * 3 + 1], yB[i * 3]));
        float Z = fmaf(s0, yC[2], fmaf(c0, yC[1], yC[0]));

        float act = fmaf(sc, fast_sig(kk, Z), -of);

        int ai2 = __float_as_int(act);
        float f  = __int_as_float(__builtin_amdgcn_update_dpp(0, ai2, 0x00, 0xf, 0xf, true));
        float ii = __int_as_float(__builtin_amdgcn_update_dpp(0, ai2, 0x55, 0xf, 0xf, true));
        float gg = __int_as_float(__builtin_amdgcn_update_dpp(0, ai2, 0xAA, 0xf, 0xf, true));
        float oo = __int_as_float(__builtin_amdgcn_update_dpp(0, ai2, 0xFF, 0xf, 0xf, true));

        cst = fmaf(f, cst, ii * gg);
        float tn = fmaf(2.f, fast_sig(2.f, cst), -1.f);
        float hme = oo * tn;

        if (g == 0) op[(size_t)sidx * 2048] = hme;

        int hi = __float_as_int(hme);
        hr0 = hme;
        hr1 = __int_as_float(__builtin_amdgcn_update_dpp(hi, hi, 0x124, 0xf, 0xf, false));
        hr2 = __int_as_float(__builtin_amdgcn_update_dpp(hi, hi, 0x128, 0xf, 0xf, false));
        hr3 = __int_as_float(__builtin_amdgcn_update_dpp(hi, hi, 0x12C, 0xf, 0xf, false));
    };

    for (int s = 0; s < S_LEN; s += 4) {
        step(A0, s);     A0 = rowat(tk0); tk0 = tokat(s + 8);
        step(A1, s + 1); A1 = rowat(tk1); tk1 = tokat(s + 9);
        step(A2, s + 2); A2 = rowat(tk2); tk2 = tokat(s + 10);
        step(A3, s + 3); A3 = rowat(tk3); tk3 = tokat(s + 11);
    }
}

// ---------------------------------------------------------------------------
// logits + log_softmax: wave per (s,b) row, lane = tag.
// ---------------------------------------------------------------------------
__global__ __launch_bounds__(256) void logits_kernel(const float* __restrict__ outs,
                                                     const float* __restrict__ tag_w,
                                                     const float* __restrict__ tag_b,
                                                     float* __restrict__ out) {
    int l = threadIdx.x & 63;
    int wid = (blockIdx.x * blockDim.x + threadIdx.x) >> 6;
    int nw  = (gridDim.x * blockDim.x) >> 6;

    float4 w = *(const float4*)(tag_w + l * 4);
    float bb = tag_b[l];

    for (int row = wid; row < ROWS; row += nw) {
        float4 h = *(const float4*)(outs + (size_t)row * 4);
        float z = fmaf(h.x, w.x, fmaf(h.y, w.y, fmaf(h.z, w.z, fmaf(h.w, w.w, bb))));
        float m = z;
#pragma unroll
        for (int d = 1; d < 64; d <<= 1) m = fmaxf(m, __shfl_xor(m, d, 64));
        float e = __expf(z - m);
        float ssum = e;
#pragma unroll
        for (int d = 1; d < 64; d <<= 1) ssum += __shfl_xor(ssum, d, 64);
        out[(size_t)row * 64 + l] = (z - m) - __logf(ssum);
    }
}

// ---------------------------------------------------------------------------
extern "C" void kernel_launch(void* const* d_in, const int* in_sizes, int n_in,
                              void* d_out, int out_size, void* d_ws, size_t ws_size,
                              hipStream_t stream) {
    const int*   sent  = (const int*)d_in[0];
    const float* emb   = (const float*)d_in[1];
    const float* lin_w = (const float*)d_in[2];
    const float* lin_b = (const float*)d_in[3];
    const float* qrx   = (const float*)d_in[4];
    const float* qry   = (const float*)d_in[5];
    const float* qrz   = (const float*)d_in[6];
    const float* qcrx  = (const float*)d_in[7];
    const float* tag_w = (const float*)d_in[8];
    const float* tag_b = (const float*)d_in[9];
    float* out = (float*)d_out;

    char* ws = (char*)d_ws;
    float*  Tg   = (float*)ws;                                     // 16*81*4 = 5184 B
    float*  proj = (float*)(ws + 8192);                            // VOCAB*16*4 = 8.192 MB
    float*  outs = (float*)(ws + 8192 + (size_t)VOCAB * 16 * 4);   // ROWS*4*4 = 2 MB

    setup_kernel<<<dim3(1), dim3(1024), 0, stream>>>(qrx, qry, qrz, qcrx, Tg);
    proj_kernel<<<dim3(2048), dim3(256), 0, stream>>>(emb, lin_w, lin_b, proj);
    lstm_kernel<<<dim3(128), dim3(64), 0, stream>>>(lin_w, Tg, sent, proj, outs);
    logits_kernel<<<dim3(1024), dim3(256), 0, stream>>>(outs, tag_w, tag_b, out);
}